// Round 6
// baseline (171.984 us; speedup 1.0000x reference)
//
#include <hip/hip_runtime.h>
#include <hip/hip_bf16.h>
#include <math.h>

#define BATCH_N 8192
#define K_DIM   2048
#define CLS     1000
#define NPAD    1024

typedef __attribute__((ext_vector_type(8))) short short8;
typedef __attribute__((ext_vector_type(8))) unsigned short ushort8;
typedef __attribute__((ext_vector_type(4))) float floatx4;

static __device__ __forceinline__ ushort f2bf(float f) {
    union { float f; unsigned u; } v; v.f = f;
    unsigned u = v.u;
    return (ushort)((u + 0x7FFFu + ((u >> 16) & 1u)) >> 16); // RNE
}

static __device__ __forceinline__ void gld_lds16(const void* g, void* l) {
    __builtin_amdgcn_global_load_lds(
        (const __attribute__((address_space(1))) void*)g,
        (__attribute__((address_space(3))) void*)l, 16, 0, 0);
}

static __device__ __forceinline__ float softplus_fast(float z) {
    return fmaxf(z, 0.f) + __logf(1.f + __expf(-fabsf(z)));
}

// ---------------- single-pass convert: x,y -> bf16; W -> bf16 padded --------
__global__ __launch_bounds__(256)
void convert_all(const float* __restrict__ x, const float* __restrict__ y,
                 const float* __restrict__ wx, const float* __restrict__ wy,
                 ushort* __restrict__ xb, ushort* __restrict__ yb,
                 ushort* __restrict__ wxb, ushort* __restrict__ wyb)
{
    int b = blockIdx.x;
    const float* src; ushort* dst; bool isw = false;
    if (b < 8192)       { src = x;  dst = xb; }
    else if (b < 16384) { src = y;  dst = yb;  b -= 8192; }
    else if (b < 17408) { src = wx; dst = wxb; b -= 16384; isw = true; }
    else                { src = wy; dst = wyb; b -= 17408; isw = true; }
    size_t e = ((size_t)b * 256 + threadIdx.x) * 8;
    ushort8 t = (ushort8)0;
    if (!isw || (int)(e >> 11) < CLS) {
        float4 a = *(const float4*)(src + e);
        float4 c = *(const float4*)(src + e + 4);
#pragma unroll
        for (int j = 0; j < 4; ++j) {
            t[j]     = f2bf(((const float*)&a)[j]);
            t[j + 4] = f2bf(((const float*)&c)[j]);
        }
    }
    *(ushort8*)(dst + e) = t;
}

// ------ 256x256 bf16 GEMM: 8-phase, counted vmcnt AND counted lgkmcnt ------
// 8 waves (2 wr x 4 wc), per-wave 128x64 out. BK=64, 2 LDS K-tile slots.
// Swizzle: chunk c8 at row r holds k-range (c8^(r&7))*8 (verified: 0 confl).
// Pipelining: ds_reads are issued ONE PHASE BEFORE their consuming MFMA
// (reads/phase: q0:4 q1:8 q2:8 q3:4) so LDS service overlaps MFMA.
// lgkm waits are counted (allow this phase's reads to stay in flight).
// gld_lds drains (VMW) sit at END of the phase BEFORE the reads, ahead of the
// closing barrier => cross-wave RAW on staged data is barrier-protected.
//   per steady tile t (slot sl=t&1):
//   q0: stage B1(t+1); read bh<-Bs[sl]h1;  lgkm(4); M0=A0xB0; vm(6)
//   q1: stage A1(t+1); read a1<-As[sl]h1;  lgkm(8); M1=A0xB1; vm(4)
//   q2: stage A0(t+2); read BLn<-Bs[sl^1]h0, a0lo<-As[sl^1]h0; lgkm(8); M2=A1xB1
//   q3: stage B0(t+2); read a0hi<-As[sl^1]h0; (no lgkm)       M3=A1xB0; vm(6)
// B-low fragments double-buffered (blA/blB) across tile parity.

constexpr int NT = K_DIM / 64;   // 32 K-tiles

#define BARX __builtin_amdgcn_s_barrier()
#define LGKMW(n) asm volatile("s_waitcnt lgkmcnt(" #n ")" ::: "memory")
#define VMW(n)   asm volatile("s_waitcnt vmcnt(" #n ")" ::: "memory")
#define PRIO1 __builtin_amdgcn_s_setprio(1)
#define PRIO0 __builtin_amdgcn_s_setprio(0)

#define STAGE_A(h, sl, t_) {                                                  \
    const size_t kb_ = (size_t)(t_) * 64;                                     \
    gld_lds16(A + aofs_g[0] + (h) * 64 * K_DIM + kb_,                         \
              &As[sl][aofs_l[0] + (h) * 4096]);                               \
    gld_lds16(A + aofs_g[1] + (h) * 64 * K_DIM + kb_,                         \
              &As[sl][aofs_l[1] + (h) * 4096]); }
#define STAGE_B(h, sl, t_) {                                                  \
    const size_t kb_ = (size_t)(t_) * 64;                                     \
    gld_lds16(B + bofs_g[0] + (h) * 32 * K_DIM + kb_,                         \
              &Bs[sl][bofs_l[0] + (h) * 2048]);                               \
    gld_lds16(B + bofs_g[1] + (h) * 32 * K_DIM + kb_,                         \
              &Bs[sl][bofs_l[1] + (h) * 2048]); }

#define LDA_LO(dst, base, h) {                                                \
    const ushort* p_ = (base) + wr * 8192 + (h) * 4096;                       \
    dst[0][0] = *(const short8*)(p_ + e0);        dst[0][1] = *(const short8*)(p_ + e1); \
    dst[1][0] = *(const short8*)(p_ + 1024 + e0); dst[1][1] = *(const short8*)(p_ + 1024 + e1); }
#define LDA_HI(dst, base, h) {                                                \
    const ushort* p_ = (base) + wr * 8192 + (h) * 4096;                       \
    dst[2][0] = *(const short8*)(p_ + 2048 + e0); dst[2][1] = *(const short8*)(p_ + 2048 + e1); \
    dst[3][0] = *(const short8*)(p_ + 3072 + e0); dst[3][1] = *(const short8*)(p_ + 3072 + e1); }
#define LDA_ALL(dst, base, h) LDA_LO(dst, base, h) LDA_HI(dst, base, h)
#define LDB_TO(dst, base, h) {                                                \
    const ushort* p_ = (base) + wc * 4096 + (h) * 2048;                       \
    dst[0][0] = *(const short8*)(p_ + e0);        dst[0][1] = *(const short8*)(p_ + e1); \
    dst[1][0] = *(const short8*)(p_ + 1024 + e0); dst[1][1] = *(const short8*)(p_ + 1024 + e1); }

#define MM(mh, nh, i, j, kk, Ar, Br)                                          \
    acc[(mh)*4+(i)][(nh)*2+(j)] = __builtin_amdgcn_mfma_f32_16x16x32_bf16(    \
        Ar[i][kk], Br[j][kk], acc[(mh)*4+(i)][(nh)*2+(j)], 0, 0, 0);
#define MQ(mh, nh, Ar, Br)                                                    \
    MM(mh,nh,0,0,0,Ar,Br) MM(mh,nh,0,1,0,Ar,Br) MM(mh,nh,1,0,0,Ar,Br) MM(mh,nh,1,1,0,Ar,Br) \
    MM(mh,nh,2,0,0,Ar,Br) MM(mh,nh,2,1,0,Ar,Br) MM(mh,nh,3,0,0,Ar,Br) MM(mh,nh,3,1,0,Ar,Br) \
    MM(mh,nh,0,0,1,Ar,Br) MM(mh,nh,0,1,1,Ar,Br) MM(mh,nh,1,0,1,Ar,Br) MM(mh,nh,1,1,1,Ar,Br) \
    MM(mh,nh,2,0,1,Ar,Br) MM(mh,nh,2,1,1,Ar,Br) MM(mh,nh,3,0,1,Ar,Br) MM(mh,nh,3,1,1,Ar,Br)

#define TILE_STEADY(t_, sl_, sl1_, BLc, BLn)                                  \
    STAGE_B(1, sl1_, (t_) + 1)                                                \
    LDB_TO(bh, &Bs[sl_][0], 1)                                                \
    BARX; LGKMW(4);                                                           \
    PRIO1; MQ(0, 0, a0, BLc) PRIO0;                                           \
    VMW(6); BARX;                                                             \
    STAGE_A(1, sl1_, (t_) + 1)                                                \
    LDA_ALL(a1, &As[sl_][0], 1)                                               \
    BARX; LGKMW(8);                                                           \
    PRIO1; MQ(0, 1, a0, bh) PRIO0;                                            \
    VMW(4); BARX;                                                             \
    STAGE_A(0, sl_, (t_) + 2)                                                 \
    LDB_TO(BLn, &Bs[sl1_][0], 0)                                              \
    LDA_LO(a0, &As[sl1_][0], 0)                                               \
    BARX; LGKMW(8);                                                           \
    PRIO1; MQ(1, 1, a1, bh) PRIO0;                                            \
    BARX;                                                                     \
    STAGE_B(0, sl_, (t_) + 2)                                                 \
    LDA_HI(a0, &As[sl1_][0], 0)                                               \
    BARX;                                                                     \
    PRIO1; MQ(1, 0, a1, BLc) PRIO0;                                           \
    VMW(6); BARX;

__global__ __launch_bounds__(512, 2)
void gemm8p(const ushort* __restrict__ Aa, const ushort* __restrict__ Ab,
            const ushort* __restrict__ Ba, const ushort* __restrict__ Bb,
            const float* __restrict__ biasa, const float* __restrict__ biasb,
            float* __restrict__ outa, float* __restrict__ outb)
{
    // bijective XCD swizzle over the 256-block grid (256 % 8 == 0)
    int flat = blockIdx.x + 4 * (blockIdx.y + 32 * blockIdx.z);
    int sw   = (flat & 7) * 32 + (flat >> 3);
    const int bx = sw & 3, by = (sw >> 2) & 31, bz = sw >> 7;

    const ushort* A   = bz ? Ab : Aa;
    const ushort* B   = bz ? Bb : Ba;
    const float* bias = bz ? biasb : biasa;
    float* out        = bz ? outb : outa;

    __shared__ ushort As[2][256 * 64];
    __shared__ ushort Bs[2][256 * 64];

    const int tid  = threadIdx.x;
    const int lane = tid & 63;
    const int wid  = tid >> 6;
    const int wr = wid >> 2, wc = wid & 3;
    const int fr = lane & 15, fg = lane >> 4;
    const int frx8 = (fr & 7) << 3;
    const int brow = by * 256;
    const int bcol = bx * 256;

    int    aofs_l[2], bofs_l[2];
    size_t aofs_g[2], bofs_g[2];
#pragma unroll
    for (int i = 0; i < 2; ++i) {
        int q = i * 512 + tid, rr = q >> 3, c8 = q & 7, c8l = c8 ^ (rr & 7);
        int ra = (rr >> 6) * 128 + (rr & 63);
        int rb = (rr >> 5) * 64  + (rr & 31);
        aofs_l[i] = ra * 64 + c8 * 8;
        bofs_l[i] = rb * 64 + c8 * 8;
        aofs_g[i] = (size_t)(brow + ra) * K_DIM + c8l * 8;
        bofs_g[i] = (size_t)(bcol + rb) * K_DIM + c8l * 8;
    }

    const int e0 = fr * 64 + ((fg * 8) ^ frx8);
    const int e1 = fr * 64 + ((32 + fg * 8) ^ frx8);

    floatx4 acc[8][4];
#pragma unroll
    for (int m = 0; m < 8; ++m)
#pragma unroll
        for (int n = 0; n < 4; ++n)
            acc[m][n] = (floatx4){0.f, 0.f, 0.f, 0.f};

    short8 a0[4][2], a1[4][2], bh[2][2], blA[2][2], blB[2][2];

    // prologue: 6 half-tiles in flight; drain A0(0),B0(0),B1(0); preload regs
    STAGE_A(0, 0, 0) STAGE_B(0, 0, 0) STAGE_B(1, 0, 0) STAGE_A(1, 0, 0)
    STAGE_A(0, 1, 1) STAGE_B(0, 1, 1)
    VMW(6); BARX;
    LDB_TO(blA, &Bs[0][0], 0)
    LDA_ALL(a0, &As[0][0], 0)

#pragma unroll 1
    for (int tt = 0; tt < (NT - 2) / 2; ++tt) {   // t = 0..29
        TILE_STEADY(2 * tt,     0, 1, blA, blB)
        TILE_STEADY(2 * tt + 1, 1, 0, blB, blA)
    }
    {   // t = NT-2 = 30 (sl=0): stages only B1(31), A1(31)
        STAGE_B(1, 1, 31)
        LDB_TO(bh, &Bs[0][0], 1)
        BARX; LGKMW(4);
        PRIO1; MQ(0, 0, a0, blA) PRIO0;
        VMW(6); BARX;
        STAGE_A(1, 1, 31)
        LDA_ALL(a1, &As[0][0], 1)
        BARX; LGKMW(8);
        PRIO1; MQ(0, 1, a0, bh) PRIO0;
        VMW(4); BARX;
        LDB_TO(blB, &Bs[1][0], 0)
        LDA_LO(a0, &As[1][0], 0)
        BARX; LGKMW(8);
        PRIO1; MQ(1, 1, a1, bh) PRIO0;
        BARX;
        LDA_HI(a0, &As[1][0], 0)
        BARX;
        PRIO1; MQ(1, 0, a1, blA) PRIO0;
        VMW(2); BARX;
    }
    {   // t = NT-1 = 31 (sl=1): no stages
        LDB_TO(bh, &Bs[1][0], 1)
        BARX; LGKMW(4);
        PRIO1; MQ(0, 0, a0, blB) PRIO0;
        VMW(0); BARX;
        LDA_ALL(a1, &As[1][0], 1)
        BARX; LGKMW(8);
        PRIO1; MQ(0, 1, a0, bh) PRIO0;
        BARX;
        BARX; LGKMW(0);
        PRIO1; MQ(1, 1, a1, bh) PRIO0;
        BARX;
        PRIO1; MQ(1, 0, a1, blB) PRIO0;
    }

    // epilogue: alpha = softplus(z + bias) + 1, predicated on col < 1000
#pragma unroll
    for (int n = 0; n < 4; ++n) {
        int col = bcol + wc * 64 + n * 16 + fr;
        if (col >= CLS) continue;
        float bv = bias[col];
#pragma unroll
        for (int m = 0; m < 8; ++m) {
#pragma unroll
            for (int j = 0; j < 4; ++j) {
                int row = brow + wr * 128 + m * 16 + fg * 4 + j;
                float z = acc[m][n][j] + bv;
                out[(size_t)row * CLS + col] = softplus_fast(z) + 1.f;
            }
        }
    }
}

// ---------------- fallback path (no workspace): fused fp32->bf16 ------------

constexpr int FBM = 128, FBN = 128, FBK = 64;
constexpr int FNKT = K_DIM / FBK;
constexpr int LDP = FBK + 8;

__global__ __launch_bounds__(256, 2)
void gemm_alpha(const float* __restrict__ Xa, const float* __restrict__ Xb,
                const float* __restrict__ Wa, const float* __restrict__ Wb,
                const float* __restrict__ ba, const float* __restrict__ bb,
                float* __restrict__ outa, float* __restrict__ outb)
{
    const float* X   = blockIdx.z ? Xb : Xa;
    const float* W   = blockIdx.z ? Wb : Wa;
    const float* bias= blockIdx.z ? bb : ba;
    float* out       = blockIdx.z ? outb : outa;

    __shared__ ushort Asf[FBM][LDP];
    __shared__ ushort Bsf[FBN][LDP];

    const int tid  = threadIdx.x;
    const int brow = blockIdx.y * FBM;
    const int bcol = blockIdx.x * FBN;

    float4 ra[4][2], rb[4][2];

    auto load_tile = [&](int kt) {
        const int kbase = kt * FBK;
#pragma unroll
        for (int i = 0; i < 4; ++i) {
            int idx = tid + i * 256;
            int row = idx >> 3;
            int c8  = (idx & 7) << 3;
            const float* pA = X + (size_t)(brow + row) * K_DIM + kbase + c8;
            ra[i][0] = *(const float4*)pA;
            ra[i][1] = *(const float4*)(pA + 4);
            int wrow = bcol + row; if (wrow >= CLS) wrow = CLS - 1;
            const float* pB = W + (size_t)wrow * K_DIM + kbase + c8;
            rb[i][0] = *(const float4*)pB;
            rb[i][1] = *(const float4*)(pB + 4);
        }
    };

    auto store_tile = [&]() {
#pragma unroll
        for (int i = 0; i < 4; ++i) {
            int idx = tid + i * 256;
            int row = idx >> 3;
            int c8  = (idx & 7) << 3;
            ushort8 ta, tb;
#pragma unroll
            for (int j = 0; j < 4; ++j) {
                ta[j]     = f2bf(((const float*)&ra[i][0])[j]);
                ta[j + 4] = f2bf(((const float*)&ra[i][1])[j]);
                tb[j]     = f2bf(((const float*)&rb[i][0])[j]);
                tb[j + 4] = f2bf(((const float*)&rb[i][1])[j]);
            }
            *(ushort8*)&Asf[row][c8] = ta;
            *(ushort8*)&Bsf[row][c8] = tb;
        }
    };

    const int lane = tid & 63;
    const int wid  = tid >> 6;
    const int wr = wid >> 1, wc = wid & 1;
    const int row0 = wr * 64, col0 = wc * 64;
    const int fr = lane & 15;
    const int fg = lane >> 4;

    floatx4 acc[4][4];
#pragma unroll
    for (int m = 0; m < 4; ++m)
#pragma unroll
        for (int n = 0; n < 4; ++n)
            acc[m][n] = (floatx4){0.f, 0.f, 0.f, 0.f};

    load_tile(0);
    for (int kt = 0; kt < FNKT; ++kt) {
        if (kt) __syncthreads();
        store_tile();
        __syncthreads();
        if (kt + 1 < FNKT) load_tile(kt + 1);
#pragma unroll
        for (int kk = 0; kk < 2; ++kk) {
            short8 af[4], bf8[4];
#pragma unroll
            for (int m = 0; m < 4; ++m)
                af[m] = *(const short8*)&Asf[row0 + m * 16 + fr][kk * 32 + fg * 8];
#pragma unroll
            for (int n = 0; n < 4; ++n)
                bf8[n] = *(const short8*)&Bsf[col0 + n * 16 + fr][kk * 32 + fg * 8];
#pragma unroll
            for (int m = 0; m < 4; ++m)
#pragma unroll
                for (int n = 0; n < 4; ++n)
                    acc[m][n] = __builtin_amdgcn_mfma_f32_16x16x32_bf16(
                        af[m], bf8[n], acc[m][n], 0, 0, 0);
        }
    }

#pragma unroll
    for (int n = 0; n < 4; ++n) {
        int col = bcol + col0 + n * 16 + fr;
        if (col >= CLS) continue;
        float bv = bias[col];
#pragma unroll
        for (int m = 0; m < 4; ++m) {
#pragma unroll
            for (int j = 0; j < 4; ++j) {
                int row = brow + row0 + m * 16 + fg * 4 + j;
                float z = acc[m][n][j] + bv;
                out[(size_t)row * CLS + col] = softplus_fast(z) + 1.f;
            }
        }
    }
}

// ---------------- DS combine: one wave per row, shuffle-xor reduce ----------

__global__ __launch_bounds__(256)
void ds_combine(const float* __restrict__ AX, const float* __restrict__ AY,
                float* __restrict__ out)
{
    const int row = blockIdx.x * 4 + (threadIdx.x >> 6);
    const int l = threadIdx.x & 63;
    const float* ax = AX + (size_t)row * CLS;
    const float* ay = AY + (size_t)row * CLS;

    float4 vx[4], vy[4];
    float sx = 0.f, sy = 0.f, sp = 0.f;
#pragma unroll
    for (int c = 0; c < 4; ++c) {
        int idx = l + c * 64;
        if (idx < CLS / 4) {
            vx[c] = *(const float4*)(ax + idx * 4);
            vy[c] = *(const float4*)(ay + idx * 4);
            const float* px = (const float*)&vx[c];
            const float* py = (const float*)&vy[c];
#pragma unroll
            for (int j = 0; j < 4; ++j) {
                sx += px[j]; sy += py[j];
                sp += (px[j] - 1.f) * (py[j] - 1.f);
            }
        }
    }
#pragma unroll
    for (int off = 1; off < 64; off <<= 1) {
        sx += __shfl_xor(sx, off);
        sy += __shfl_xor(sy, off);
        sp += __shfl_xor(sp, off);
    }
    const float S1 = sx, S2 = sy, P = sp;
    const float i1 = 1.f / S1, i2 = 1.f / S2;
    const float u1 = (float)CLS * i1, u2 = (float)CLS * i2;
    const float sb1 = (S1 - (float)CLS) * i1;
    const float sb2 = (S2 - (float)CLS) * i2;
    const float conf = sb1 * sb2 - P * i1 * i2;
    const float denom = 1.f - conf;
    const float idenom = 1.f / denom;
    const float Sa = (float)CLS * denom / (u1 * u2);

#pragma unroll
    for (int c = 0; c < 4; ++c) {
        int idx = l + c * 64;
        if (idx < CLS / 4) {
            float4 vo;
            const float* px = (const float*)&vx[c];
            const float* py = (const float*)&vy[c];
            float* po = (float*)&vo;
#pragma unroll
            for (int j = 0; j < 4; ++j) {
                float b1 = (px[j] - 1.f) * i1;
                float b2 = (py[j] - 1.f) * i2;
                float ba = (b1 * b2 + b1 * u2 + b2 * u1) * idenom;
                po[j] = ba * Sa + 1.f;
            }
            *(float4*)(out + (size_t)row * CLS + idx * 4) = vo;
        }
    }
}

extern "C" void kernel_launch(void* const* d_in, const int* in_sizes, int n_in,
                              void* d_out, int out_size, void* d_ws, size_t ws_size,
                              hipStream_t stream) {
    const float* x  = (const float*)d_in[0];
    const float* y  = (const float*)d_in[1];
    const float* Wx = (const float*)d_in[2];
    const float* bx = (const float*)d_in[3];
    const float* Wy = (const float*)d_in[4];
    const float* by = (const float*)d_in[5];
    float* out = (float*)d_out;
    float* ax = out + (size_t)BATCH_N * CLS;
    float* ay = ax  + (size_t)BATCH_N * CLS;

    const size_t SZ_X = (size_t)BATCH_N * K_DIM;
    const size_t SZ_W = (size_t)NPAD * K_DIM;
    const size_t need = (2 * SZ_X + 2 * SZ_W) * sizeof(ushort); // 75.5 MB

    if (ws_size >= need) {
        ushort* xb  = (ushort*)d_ws;
        ushort* yb  = xb + SZ_X;
        ushort* wxb = yb + SZ_X;
        ushort* wyb = wxb + SZ_W;

        convert_all<<<18432, 256, 0, stream>>>(x, y, Wx, Wy, xb, yb, wxb, wyb);
        gemm8p<<<dim3(NPAD / 256, BATCH_N / 256, 2), 512, 0, stream>>>(
            xb, yb, wxb, wyb, bx, by, ax, ay);
    } else {
        gemm_alpha<<<dim3((CLS + FBN - 1) / FBN, BATCH_N / FBM, 2), 256, 0, stream>>>(
            x, y, Wx, Wy, bx, by, ax, ay);
    }
    ds_combine<<<BATCH_N / 4, 256, 0, stream>>>(ax, ay, out);
}

// Round 7
// 109.789 us; speedup vs baseline: 1.5665x; 1.5665x over previous
//
#include <hip/hip_runtime.h>
#include <hip/hip_bf16.h>
#include <math.h>

#define BATCH_N 8192
#define K_DIM   2048
#define CLS     1000

typedef __attribute__((ext_vector_type(8))) short short8;
typedef __attribute__((ext_vector_type(8))) unsigned short ushort8;
typedef __attribute__((ext_vector_type(4))) float floatx4;

static __device__ __forceinline__ float softplus_fast(float z) {
    return fmaxf(z, 0.f) + __logf(1.f + __expf(-fabsf(z)));
}

// ---- 256x256 GEMM, fused fp32->bf16 staging, BK=32, 2-slot dbuf, 1 bar/tile
// 8 waves (2 wr x 4 wc), per-wave 128x64 output, 32 MFMA/wave/tile.
// LDS slot layout (per operand): 1024 16B-chunks; chunk q holds logical
// (row r, k-range) with p=q>>3, c8l=(q&7)^(p&7), r=2p+(c8l>>2), k=(c8l&3)*8.
// (Round-4-verified: correct results, 0 bank conflicts.) Staging is explicit
// ds_write_b128 (swizzle on both sides trivially); global fp32 loads are
// coalesced (8 lanes cover two 128B row segments, permuted within).
// Sync: lgkmcnt(0) + raw s_barrier per tile. NO vmcnt drain at the barrier:
// global loads feed only the loading wave's own cvt (no cross-wave dep), so
// prefetched loads stay in flight across barriers (the m97 stall removed).

constexpr int NT = K_DIM / 32;   // 64 K-tiles

#define BARX  __builtin_amdgcn_s_barrier()
#define LGKM0 asm volatile("s_waitcnt lgkmcnt(0)" ::: "memory")
#define SB0   __builtin_amdgcn_sched_barrier(0)
#define PRIO1 __builtin_amdgcn_s_setprio(1)
#define PRIO0 __builtin_amdgcn_s_setprio(0)

__global__ __launch_bounds__(512, 2)
void gemm_fused(const float* __restrict__ Xa, const float* __restrict__ Xb,
                const float* __restrict__ Wa, const float* __restrict__ Wb,
                const float* __restrict__ biasa, const float* __restrict__ biasb,
                float* __restrict__ outa, float* __restrict__ outb)
{
    // bijective XCD swizzle over the 256-block grid (256 % 8 == 0)
    int flat = blockIdx.x + 4 * (blockIdx.y + 32 * blockIdx.z);
    int sw   = (flat & 7) * 32 + (flat >> 3);
    const int bx = sw & 3, by = (sw >> 2) & 31, bz = sw >> 7;

    const float* A    = bz ? Xb : Xa;       // [8192][2048] fp32
    const float* B    = bz ? Wb : Wa;       // [1000][2048] fp32
    const float* bias = bz ? biasb : biasa;
    float* out        = bz ? outb : outa;

    __shared__ ushort As[2][256 * 32];      // 16 KiB per slot
    __shared__ ushort Bs[2][256 * 32];

    const int tid  = threadIdx.x;
    const int lane = tid & 63;
    const int wid  = tid >> 6;              // 8 waves: wr in {0,1}, wc in {0..3}
    const int wr = wid >> 2, wc = wid & 3;
    const int fr = lane & 15, fg = lane >> 4;
    const int brow = by * 256;
    const int bcol = bx * 256;

    // staging map: thread handles chunks q = tid, tid+512 (per operand)
    size_t a_g[2], b_g[2];
    int    l_of[2];
#pragma unroll
    for (int i = 0; i < 2; ++i) {
        int q = tid + i * 512;
        int p = q >> 3, c8 = q & 7, c8l = c8 ^ (p & 7);
        int r = 2 * p + (c8l >> 2);
        int k = (c8l & 3) * 8;
        a_g[i] = (size_t)(brow + r) * K_DIM + k;
        int wrow = bcol + r; if (wrow >= CLS) wrow = CLS - 1;   // clamp pad rows
        b_g[i] = (size_t)wrow * K_DIM + k;
        l_of[i] = q * 8;                    // ushorts
    }

    // fragment-read offsets (round-4-verified layout)
    int afoff[8], bfoff[4];
#pragma unroll
    for (int m = 0; m < 8; ++m) {
        int row = wr * 128 + m * 16 + fr;
        int p = row >> 1;
        int c = (((row & 1) << 2) | fg) ^ (p & 7);
        afoff[m] = (p * 8 + c) * 8;
    }
#pragma unroll
    for (int n = 0; n < 4; ++n) {
        int row = wc * 64 + n * 16 + fr;
        int p = row >> 1;
        int c = (((row & 1) << 2) | fg) ^ (p & 7);
        bfoff[n] = (p * 8 + c) * 8;
    }

    floatx4 acc[8][4];
#pragma unroll
    for (int m = 0; m < 8; ++m)
#pragma unroll
        for (int n = 0; n < 4; ++n)
            acc[m][n] = (floatx4){0.f, 0.f, 0.f, 0.f};

    float4 ga[2][2], gb[2][2];              // staged fp32 (tile in flight)

#define LOADT(t_) {                                                           \
    const size_t kb_ = (size_t)(t_) * 32;                                     \
    ga[0][0] = *(const float4*)(A + a_g[0] + kb_);                            \
    ga[0][1] = *(const float4*)(A + a_g[0] + kb_ + 4);                        \
    ga[1][0] = *(const float4*)(A + a_g[1] + kb_);                            \
    ga[1][1] = *(const float4*)(A + a_g[1] + kb_ + 4);                        \
    gb[0][0] = *(const float4*)(B + b_g[0] + kb_);                            \
    gb[0][1] = *(const float4*)(B + b_g[0] + kb_ + 4);                        \
    gb[1][0] = *(const float4*)(B + b_g[1] + kb_);                            \
    gb[1][1] = *(const float4*)(B + b_g[1] + kb_ + 4);                        \
}

#define CVTW(sl_) {                                                           \
    _Pragma("unroll")                                                         \
    for (int i = 0; i < 2; ++i) {                                             \
        ushort8 ta, tb;                                                       \
        _Pragma("unroll")                                                     \
        for (int j = 0; j < 4; ++j) {                                         \
            ta[j]     = __hip_bfloat16_raw(__float2bfloat16(((const float*)&ga[i][0])[j])).x; \
            ta[j + 4] = __hip_bfloat16_raw(__float2bfloat16(((const float*)&ga[i][1])[j])).x; \
            tb[j]     = __hip_bfloat16_raw(__float2bfloat16(((const float*)&gb[i][0])[j])).x; \
            tb[j + 4] = __hip_bfloat16_raw(__float2bfloat16(((const float*)&gb[i][1])[j])).x; \
        }                                                                     \
        *(ushort8*)&As[sl_][l_of[i]] = ta;                                    \
        *(ushort8*)&Bs[sl_][l_of[i]] = tb;                                    \
    }                                                                         \
}

    // prologue: tile 0 staged to slot 0; tile 1 loads in flight
    LOADT(0)
    CVTW(0)
    LOADT(1)
    SB0; LGKM0; BARX; SB0;

#pragma unroll 1
    for (int t = 0; t < NT; ++t) {
        const ushort* asl = &As[t & 1][0];
        const ushort* bsl = &Bs[t & 1][0];
        short8 af[8], bf[4];
#pragma unroll
        for (int m = 0; m < 8; ++m) af[m] = *(const short8*)(asl + afoff[m]);
#pragma unroll
        for (int n = 0; n < 4; ++n) bf[n] = *(const short8*)(bsl + bfoff[n]);

        PRIO1;
#pragma unroll
        for (int m = 0; m < 8; ++m)
#pragma unroll
            for (int n = 0; n < 4; ++n)
                acc[m][n] = __builtin_amdgcn_mfma_f32_16x16x32_bf16(
                    af[m], bf[n], acc[m][n], 0, 0, 0);
        PRIO0;

        if (t + 1 < NT) CVTW((t + 1) & 1)       // consumes loads of tile t+1
        if (t + 2 < NT) LOADT(t + 2)            // issue early; used next iter
        SB0; LGKM0; BARX; SB0;                  // NO vmcnt drain
    }

    // epilogue: alpha = softplus(z + bias) + 1, predicated on col < 1000
#pragma unroll
    for (int n = 0; n < 4; ++n) {
        int col = bcol + wc * 64 + n * 16 + fr;
        if (col >= CLS) continue;
        float bv = bias[col];
#pragma unroll
        for (int m = 0; m < 8; ++m) {
#pragma unroll
            for (int j = 0; j < 4; ++j) {
                int row = brow + wr * 128 + m * 16 + fg * 4 + j;
                float z = acc[m][n][j] + bv;
                out[(size_t)row * CLS + col] = softplus_fast(z) + 1.f;
            }
        }
    }
}

// ---------------- DS combine: one wave per row, shuffle-xor reduce ----------

__global__ __launch_bounds__(256)
void ds_combine(const float* __restrict__ AX, const float* __restrict__ AY,
                float* __restrict__ out)
{
    const int row = blockIdx.x * 4 + (threadIdx.x >> 6);
    const int l = threadIdx.x & 63;
    const float* ax = AX + (size_t)row * CLS;
    const float* ay = AY + (size_t)row * CLS;

    float4 vx[4], vy[4];
    float sx = 0.f, sy = 0.f, sp = 0.f;
#pragma unroll
    for (int c = 0; c < 4; ++c) {
        int idx = l + c * 64;
        if (idx < CLS / 4) {
            vx[c] = *(const float4*)(ax + idx * 4);
            vy[c] = *(const float4*)(ay + idx * 4);
            const float* px = (const float*)&vx[c];
            const float* py = (const float*)&vy[c];
#pragma unroll
            for (int j = 0; j < 4; ++j) {
                sx += px[j]; sy += py[j];
                sp += (px[j] - 1.f) * (py[j] - 1.f);
            }
        }
    }
#pragma unroll
    for (int off = 1; off < 64; off <<= 1) {
        sx += __shfl_xor(sx, off);
        sy += __shfl_xor(sy, off);
        sp += __shfl_xor(sp, off);
    }
    const float S1 = sx, S2 = sy, P = sp;
    const float i1 = 1.f / S1, i2 = 1.f / S2;
    const float u1 = (float)CLS * i1, u2 = (float)CLS * i2;
    const float sb1 = (S1 - (float)CLS) * i1;
    const float sb2 = (S2 - (float)CLS) * i2;
    const float conf = sb1 * sb2 - P * i1 * i2;
    const float denom = 1.f - conf;
    const float idenom = 1.f / denom;
    const float Sa = (float)CLS * denom / (u1 * u2);

#pragma unroll
    for (int c = 0; c < 4; ++c) {
        int idx = l + c * 64;
        if (idx < CLS / 4) {
            float4 vo;
            const float* px = (const float*)&vx[c];
            const float* py = (const float*)&vy[c];
            float* po = (float*)&vo;
#pragma unroll
            for (int j = 0; j < 4; ++j) {
                float b1 = (px[j] - 1.f) * i1;
                float b2 = (py[j] - 1.f) * i2;
                float ba = (b1 * b2 + b1 * u2 + b2 * u1) * idenom;
                po[j] = ba * Sa + 1.f;
            }
            *(float4*)(out + (size_t)row * CLS + idx * 4) = vo;
        }
    }
}

extern "C" void kernel_launch(void* const* d_in, const int* in_sizes, int n_in,
                              void* d_out, int out_size, void* d_ws, size_t ws_size,
                              hipStream_t stream) {
    const float* x  = (const float*)d_in[0];
    const float* y  = (const float*)d_in[1];
    const float* Wx = (const float*)d_in[2];
    const float* bx = (const float*)d_in[3];
    const float* Wy = (const float*)d_in[4];
    const float* by = (const float*)d_in[5];
    float* out = (float*)d_out;
    float* ax = out + (size_t)BATCH_N * CLS;
    float* ay = ax  + (size_t)BATCH_N * CLS;

    gemm_fused<<<dim3(4, 32, 2), 512, 0, stream>>>(
        x, y, Wx, Wy, bx, by, ax, ay);
    ds_combine<<<BATCH_N / 4, 256, 0, stream>>>(ax, ay, out);
}